// Round 6
// baseline (206.589 us; speedup 1.0000x reference)
//
#include <hip/hip_runtime.h>
#include <math.h>

// Problem constants (fixed by the reference).
#define BB    1024
#define SS    277
#define RR    76
#define ZZ    56
#define NLHS  24
#define NROWS (BB*SS)                      // 283648
#define ROWS_PER_BLOCK 256                 // rows per group (reduction unit, bit-exact)
#define NBCE (NROWS/ROWS_PER_BLOCK)        // 1108 groups
#define NMOM ZZ                            // 56 mom partials (first in layout)
#define NBLK (NBCE + NMOM)                 // 1164 partials (layout unchanged)
#define F4ROW 19                           // 76 floats = 19 float4 per row
#define BLK_ELEMS (ROWS_PER_BLOCK*RR)      // 19456
#define ROWS_PER_WAVE 64
#define F4WAVE (ROWS_PER_WAVE*F4ROW)       // 1216 float4 per wave
#define NMASK (NLHS*RR)                    // 1824
#define NMASK4 (NMASK/4)                   // 456 (exact)
#define TOTAL_ELEMS 21558272.0             // harness-verified constant

static_assert(NROWS % ROWS_PER_BLOCK == 0, "rows divide groups");
static_assert(NMASK4*4 == NMASK, "masks divisible by float4");

#define LN2F  0.69314718056f
#define NLN2F (-144.26950409f)   /* -100 / ln2 */

// Opaque 16B global load: compiler cannot rematerialize/re-read the result
// (it can't see a load at all), so the 19 row float4s MUST stay in VGPRs.
// Consumption is fenced manually: s_waitcnt vmcnt(0) + sched_barrier(0)
// (rule #18 — reg-only consumers can hoist past an asm waitcnt otherwise).
__device__ __forceinline__ float4 gload16(const float* p) {
    float4 r;
    asm volatile("global_load_dwordx4 %0, %1, off"
                 : "=v"(r)
                 : "v"((unsigned long long)p));
    return r;
}

// R9: R8's wave-autonomous structure (no block-wide vmcnt drains; per-wave
// tables; verbatim math) but the model row lives in REGISTERS, not LDS.
// Evidence: R8 at 76us showed VALUBusy 22% / HBM 14% / occupancy 17% = all
// pipes idle, latency-bound. LDS caps resident rows at 160KB/304B ~= 8
// waves/CU; the register file is 3x bigger. Inline-asm loads pin the row
// (R4's compiler-visible loads got silently demoted to re-reads, VGPR=56).
// Phases are serialized per wave (masks->tables, targets->scan, model->
// compute) to hold peak live regs ~110 < 128 so __launch_bounds__(256,4)
// gives 4 waves/SIMD = 16 waves/CU, 2x R8. LDS = ~3KB tables only.
struct BceShared {
    unsigned int  swb[4][NLHS*4];               // per-wave 96-bit masks (padded)
    int           swl[4][RR];                   // per-wave lhs table
    unsigned char sidx[4][ROWS_PER_WAVE];       // per-wave one-hot idx
    float         sm_red[4];
};
struct MomShared {
    float sdot[4][64];
    float ssum[4];
};
union SharedU { BceShared b; MomShared m; };

__global__ __launch_bounds__(256, 4) void fused_kernel(
    const float* __restrict__ model,
    const float* __restrict__ target,
    const float* __restrict__ masks,
    const int*   __restrict__ ind_to_lhs,
    const float* __restrict__ mu,
    double* __restrict__ partials)
{
    __shared__ SharedU sh;
    const int tid = threadIdx.x;

    if (blockIdx.x < NMOM) {
        // ---------------- mom path: var[:,j] for j = blockIdx (verbatim) ----
        const int j    = blockIdx.x;
        const int w    = tid >> 6;
        const int lane = tid & 63;
        const int i    = (lane < ZZ) ? lane : 0;
        float dot = 0.f, s1 = 0.f;
        const int b0 = 256*w;
        #pragma unroll 4
        for (int b = b0; b < b0 + 256; ++b) {
            const float c = mu[b*ZZ + j];     // wave-uniform broadcast
            const float a = mu[b*ZZ + i];     // coalesced across lanes
            dot = fmaf(a, c, dot);
            s1 += c;
        }
        sh.m.sdot[w][lane] = dot;
        if (lane == 0) sh.m.ssum[w] = s1;
        __syncthreads();
        if (w == 0) {
            float term = 0.f;
            if (lane < ZZ) {
                const float var = (sh.m.sdot[0][lane]+sh.m.sdot[1][lane]+sh.m.sdot[2][lane]+sh.m.sdot[3][lane]) * (1.f/BB);
                const float ve  = var - ((lane == j) ? 1.f : 0.f);
                term = tanhf(ve) * ve * (1.f/(ZZ*ZZ));
                if (lane == j) {
                    const float am = (sh.m.ssum[0]+sh.m.ssum[1]+sh.m.ssum[2]+sh.m.ssum[3]) * (1.f/BB);
                    term = fmaf(am*am, 1.f/ZZ, term);
                }
            }
            #pragma unroll
            for (int off = 32; off; off >>= 1) term += __shfl_xor(term, off, 64);
            if (lane == 0) partials[blockIdx.x] = (double)term;
        }
        return;
    }

    // ---------------- bce path: 4 autonomous waves, 64 rows each ------------
    const int bce_blk = blockIdx.x - NMOM;
    const int w    = tid >> 6;
    const int lane = tid & 63;
    const size_t blk_base = (size_t)bce_blk * BLK_ELEMS;

    // ---- phase 1: masks -> per-wave tables (mv dies before targets load,
    // bounding peak VGPR). Compiler-visible loads; it inserts exact waits.
    if (lane < 48) { sh.b.swb[w][lane] = 0u; sh.b.swb[w][lane + 48] = 0u; }
    {
        const float4* m4 = (const float4*)masks;
        float4 mv[8];
        #pragma unroll
        for (int k = 0; k < 7; ++k) mv[k] = m4[lane + 64*k];
        mv[7] = (lane + 448 < NMASK4) ? m4[lane + 448] : make_float4(0.f,0.f,0.f,0.f);
        #pragma unroll
        for (int k = 0; k < 8; ++k) {
            const int q = lane + 64*k;
            if (q < NMASK4) {
                const float4 m = mv[k];
                #pragma unroll
                for (int c = 0; c < 4; ++c) {
                    if ((&m.x)[c] > 0.5f) {
                        const int e   = q*4 + c;
                        const int lhs = e / RR;
                        const int r   = e - lhs*RR;
                        atomicOr(&sh.b.swb[w][lhs*4 + (r >> 5)], 1u << (r & 31));
                    }
                }
            }
        }
    }
    sh.b.swl[w][lane] = ind_to_lhs[lane];
    if (lane < RR-64) sh.b.swl[w][64 + lane] = ind_to_lhs[64 + lane];
    sh.b.sidx[w][lane] = 0;   // safety (one-hot always overwrites)

    // ---- phase 2: this wave's targets -> one-hot scan (t dies after).
    // A float4 never straddles rows (76 = 19 f4); one writer per row.
    {
        const float4* t4 = (const float4*)(target + blk_base) + w*F4WAVE;
        float4 t[F4ROW];
        #pragma unroll
        for (int k = 0; k < F4ROW; ++k) t[k] = t4[k*64 + lane];
        #pragma unroll
        for (int k = 0; k < F4ROW; ++k) {
            const int v4 = w*F4WAVE + k*64 + lane;    // block-local f4 index
            const float4 tv = t[k];
            int he = -1;
            const int e = v4*4;
            if (tv.x > 0.5f) he = e;
            if (tv.y > 0.5f) he = e+1;
            if (tv.z > 0.5f) he = e+2;
            if (tv.w > 0.5f) he = e+3;
            if (he >= 0) {
                const int row = he / RR;              // in [w*64, w*64+64)
                sh.b.sidx[w][row - w*ROWS_PER_WAVE] = (unsigned char)(he - row*RR);
            }
        }
    }

    // Row parameters from wave-local tables (compiler lgkmcnt; wave-local
    // program order, no barrier needed — R8-proven).
    const int true_r = (int)sh.b.sidx[w][lane];
    const int lhs    = sh.b.swl[w][true_r];
    const unsigned int mw0 = sh.b.swb[w][lhs*4 + 0];
    const unsigned int mw1 = sh.b.swb[w][lhs*4 + 1];
    const unsigned int mw2 = sh.b.swb[w][lhs*4 + 2];

    // ---- phase 3: model row -> REGISTERS via opaque asm loads (coalesced:
    // lane-consecutive float4 within the wave's 64-row span).
    float4 x[F4ROW];
    {
        const float* g = (const float*)((const float4*)(model + blk_base) + w*F4WAVE);
        #pragma unroll
        for (int k = 0; k < F4ROW; ++k)
            x[k] = gload16(g + (k*64 + lane)*4);
    }
    asm volatile("s_waitcnt vmcnt(0)" ::: "memory");
    __builtin_amdgcn_sched_barrier(0);

    // --- per-row compute from registers (verbatim R5/R8 op sequence) ---

    // Pass A: masked row max.
    float mx = -1e30f;
    #pragma unroll
    for (int k = 0; k < F4ROW; ++k) {
        const float4 v = x[k];
        #pragma unroll
        for (int c = 0; c < 4; ++c) {
            const int r = k*4 + c;
            const unsigned int mw = (r < 32) ? mw0 : ((r < 64) ? mw1 : mw2);
            const bool un = (mw >> (r & 31)) & 1u;
            const float xm = un ? (&v.x)[c] : -1e30f;
            mx = fmaxf(mx, xm);
        }
    }

    // Pass B: e_r = exp(x_r - mx) (masked -> 0), sum.
    float s = 0.f;
    #pragma unroll
    for (int k = 0; k < F4ROW; ++k) {
        const float4 v = x[k];
        #pragma unroll
        for (int c = 0; c < 4; ++c) {
            const int r = k*4 + c;
            const unsigned int mw = (r < 32) ? mw0 : ((r < 64) ? mw1 : mw2);
            const bool un = (mw >> (r & 31)) & 1u;
            const float xm = un ? (&v.x)[c] : -1e30f;
            s += __expf(xm - mx);
        }
    }

    // Pass C: clamped log(1-p) over ALL r (log2-domain), plus p at target.
    const float inv = 1.f / s;
    float sum_l2 = 0.f;
    float p_true = 0.f;
    #pragma unroll
    for (int k = 0; k < F4ROW; ++k) {
        const float4 v = x[k];
        #pragma unroll
        for (int c = 0; c < 4; ++c) {
            const int r = k*4 + c;
            const unsigned int mw = (r < 32) ? mw0 : ((r < 64) ? mw1 : mw2);
            const bool un = (mw >> (r & 31)) & 1u;
            const float xm = un ? (&v.x)[c] : -1e30f;
            const float ev = __expf(xm - mx);
            const float p  = ev * inv;
            const float l2 = __log2f(1.f - p);
            sum_l2 += fmaxf(l2, NLN2F);
            if (r == true_r) p_true = p;
        }
    }
    float row_sum = LN2F * sum_l2;
    // Swap the true_r element's non-target term for the target term.
    const float l1c_t = fmaxf(LN2F * __log2f(1.f - p_true), -100.f);
    const float lp_t  = fmaxf(__logf(p_true), -100.f);   // p_true==0 (masked) -> -100
    row_sum += lp_t - l1c_t;

    // Block reduce (identical grouping: wave butterfly, (s0+s1)+(s2+s3)).
    #pragma unroll
    for (int off = 32; off; off >>= 1) row_sum += __shfl_xor(row_sum, off, 64);
    if (lane == 0) sh.b.sm_red[w] = row_sum;
    __syncthreads();   // only block-wide barrier; nothing left outstanding
    if (tid == 0)
        partials[blockIdx.x] = (double)((sh.b.sm_red[0] + sh.b.sm_red[1]) + (sh.b.sm_red[2] + sh.b.sm_red[3]));
}

// Sum NBCE bce partials + NMOM mom partials with the right scales. (Unchanged.)
__global__ __launch_bounds__(256) void final_kernel(
    const double* __restrict__ partials, float* __restrict__ out)
{
    __shared__ double sred[4];
    const int tid = threadIdx.x;
    double s = 0.0;
    for (int k = NMOM + tid; k < NBLK; k += 256) s += partials[k];
    double m = (tid < NMOM) ? partials[tid] : 0.0;
    double val = s * (-(double)SS / TOTAL_ELEMS) + m;
    #pragma unroll
    for (int off = 32; off; off >>= 1) val += __shfl_xor(val, off, 64);
    if ((tid & 63) == 0) sred[tid >> 6] = val;
    __syncthreads();
    if (tid == 0) out[0] = (float)((sred[0] + sred[1]) + (sred[2] + sred[3]));
}

extern "C" void kernel_launch(void* const* d_in, const int* in_sizes, int n_in,
                              void* d_out, int out_size, void* d_ws, size_t ws_size,
                              hipStream_t stream) {
    const float* model  = (const float*)d_in[0];   // [B,S,R]
    const float* mu     = (const float*)d_in[1];   // [B,Z]
    // d_in[2] = log_var — unused by the reference output
    const float* target = (const float*)d_in[3];   // [B,S,R] one-hot
    const float* masks  = (const float*)d_in[4];   // [NLHS,R]
    const int*   ind    = (const int*)  d_in[5];   // [R]
    float* out  = (float*)d_out;
    double* acc = (double*)d_ws;   // [0..NMOM) mom partials, [NMOM..NBLK) bce partials

    fused_kernel<<<NBLK, ROWS_PER_BLOCK, 0, stream>>>(model, target, masks, ind, mu, acc);
    final_kernel<<<1, 256, 0, stream>>>(acc, out);
}